// Round 4
// baseline (417.552 us; speedup 1.0000x reference)
//
#include <hip/hip_runtime.h>
#include <math.h>

// ---------------------------------------------------------------------------
// QuantumTransformerE2E on MI355X — R4.
// k_chunk: R3 structure, but all weight loads at use sites (no spill under
//          __launch_bounds__(128,6)), and the seq-attention score (old k_scl)
//          fused into the tail. Writes cf + scl.
// k_pool:  256 threads: softmax + half-split pooling + 4-way-split classifier.
// ---------------------------------------------------------------------------

constexpr int kNQ    = 6;
constexpr int kDM    = 128;
constexpr int kCH    = 4;
constexpr int kSEQ   = 2048;
constexpr int kCHUNK = 16;
constexpr int kBATCH = 128;
constexpr int kNCH   = kSEQ / kCHUNK;  // 128
constexpr int kNP    = 120;
constexpr float kPI  = 3.14159265358979323846f;

__device__ __forceinline__ float fast_tanh(float x) {
  float e = __expf(-2.f * fabsf(x));
  float r = (1.f - e) * __builtin_amdgcn_rcpf(1.f + e);
  return copysignf(r, x);
}

__device__ __forceinline__ float fast_silu(float x) {
  return x * __builtin_amdgcn_rcpf(1.f + __expf(-x));
}

// ---- gates: cs = (cos(t/2), sin(t/2)); qubit w <-> bit (5-w) of lane ------

__device__ __forceinline__ void g_rx(float2 cs, int w, int lane, float& ar, float& ai) {
  int m = 1 << (5 - w);
  float pr = __shfl_xor(ar, m, 64);
  float pi = __shfl_xor(ai, m, 64);
  float nr = fmaf(cs.x, ar,  cs.y * pi);
  float ni = fmaf(cs.x, ai, -cs.y * pr);
  ar = nr; ai = ni;
}

__device__ __forceinline__ void g_ry(float2 cs, int w, int lane, float& ar, float& ai) {
  int m = 1 << (5 - w);
  float pr = __shfl_xor(ar, m, 64);
  float pi = __shfl_xor(ai, m, 64);
  float sg = ((lane >> (5 - w)) & 1) ? cs.y : -cs.y;
  float nr = fmaf(cs.x, ar, sg * pr);
  float ni = fmaf(cs.x, ai, sg * pi);
  ar = nr; ai = ni;
}

__device__ __forceinline__ void g_rz(float2 cs, int w, int lane, float& ar, float& ai) {
  float sp = ((lane >> (5 - w)) & 1) ? cs.y : -cs.y;
  float nr = fmaf(ar, cs.x, -ai * sp);
  float ni = fmaf(ar, sp,  ai * cs.x);
  ar = nr; ai = ni;
}

__device__ __forceinline__ void g_crx(float2 cs, int w0, int w1, int lane, float& ar, float& ai) {
  int m = 1 << (5 - w1);
  float pr = __shfl_xor(ar, m, 64);
  float pi = __shfl_xor(ai, m, 64);
  if ((lane >> (5 - w0)) & 1) {
    float nr = fmaf(cs.x, ar,  cs.y * pi);
    float ni = fmaf(cs.x, ai, -cs.y * pr);
    ar = nr; ai = ni;
  }
}

__device__ __forceinline__ void apply_ansatz(const float2* cs, int lane, float& ar, float& ai) {
#pragma unroll
  for (int i = 0; i < kNQ; ++i) {
    g_rx(cs[3 * i + 0], i, lane, ar, ai);
    g_ry(cs[3 * i + 1], i, lane, ar, ai);
    g_rz(cs[3 * i + 2], i, lane, ar, ai);
  }
  int off = 3 * kNQ;
#pragma unroll
  for (int i = 0; i < kNQ; ++i) g_crx(cs[off++], i, (i + 1) % kNQ, lane, ar, ai);
#pragma unroll
  for (int i = kNQ - 1; i >= 0; --i) g_crx(cs[off++], i, (i + 5) % kNQ, lane, ar, ai);
}

// ---------------------------------------------------------------------------

__global__ __launch_bounds__(128, 6) void k_chunk(
    const float* __restrict__ x,
    const float* __restrict__ conv_w, const float* __restrict__ conv_b,
    const float* __restrict__ ln1_g,  const float* __restrict__ ln1_b,
    const float* __restrict__ ca1_w,  const float* __restrict__ ca1_b,
    const float* __restrict__ ca2_w,  const float* __restrict__ ca2_b,
    const float* __restrict__ pp_w,   const float* __restrict__ pp_b,
    const float* __restrict__ ep_w,   const float* __restrict__ ep_b,
    const float* __restrict__ op_w,   const float* __restrict__ op_b,
    const float* __restrict__ ln2_g,  const float* __restrict__ ln2_b,
    const float* __restrict__ sa1_w,  const float* __restrict__ sa1_b,
    const float* __restrict__ sa2_w,  const float* __restrict__ sa2_b,
    float* __restrict__ cf, float* __restrict__ sclb)
{
  __shared__ float hbuf[kCHUNK][132];        // 8448 B, rows 16B-aligned
  __shared__ __align__(16) float Bu[512];    // 2048 B overlaid union region
  __shared__ float mrow[kCHUNK], irow[kCHUNK];
  __shared__ float red[4];

  // union views (disjoint lifetimes):
  float (*xs)[kCHUNK + 2] = (float(*)[kCHUNK + 2])Bu;  // [4][18], conv halo
  float (*part)[32]       = (float(*)[32])Bu;          // [16][32], GEMV partials
  float*  summ = Bu;                                   // [128]
  float*  wl   = Bu + 128;                             // [16]
  float*  qv   = Bu + 144;                             // [18]
  float2* csb  = (float2*)(Bu + 164);                  // [126]

  const int tid   = threadIdx.x;
  const int chunk = blockIdx.x;
  const int b     = chunk >> 7;
  const int nc    = chunk & 127;
  const int t0    = nc * kCHUNK;
  const int d     = tid;
  const int j     = tid & 31;
  const int sub   = tid >> 5;                // 0..3

  // ---- stage x halo ----
  if (tid < kCH * (kCHUNK + 2)) {
    int ch  = tid / (kCHUNK + 2);
    int pos = tid % (kCHUNK + 2);
    int s   = t0 - 1 + pos;
    float v = 0.f;
    if (s >= 0 && s < kSEQ) v = x[(b * kCH + ch) * kSEQ + s];
    xs[ch][pos] = v;
  }

  // conv weights: used immediately after the halo barrier
  float w12[12];
  {
    const float4* cw = (const float4*)(conv_w + d * 12);
    float4 a0 = cw[0], a1 = cw[1], a2 = cw[2];
    w12[0] = a0.x; w12[1]  = a0.y; w12[2]  = a0.z; w12[3]  = a0.w;
    w12[4] = a1.x; w12[5]  = a1.y; w12[6]  = a1.z; w12[7]  = a1.w;
    w12[8] = a2.x; w12[9]  = a2.y; w12[10] = a2.z; w12[11] = a2.w;
  }
  float cb = conv_b[d];
  float g1 = ln1_g[d], b1 = ln1_b[d];
  __syncthreads();

  // ---- conv1d -> hbuf ----
#pragma unroll
  for (int t = 0; t < kCHUNK; ++t) {
    float acc = cb;
#pragma unroll
    for (int ch = 0; ch < kCH; ++ch)
#pragma unroll
      for (int k = 0; k < 3; ++k)
        acc = fmaf(xs[ch][t + k], w12[ch * 3 + k], acc);
    hbuf[t][d] = acc;
  }
  __syncthreads();

  // ---- LN1 stats: 8 lanes per row, shfl combine ----
  {
    int row = tid >> 3, k = tid & 7;
    const float4* rp = (const float4*)&hbuf[row][k * 16];
    float s1 = 0.f, s2 = 0.f;
#pragma unroll
    for (int q = 0; q < 4; ++q) {
      float4 v = rp[q];
      s1 += v.x + v.y + v.z + v.w;
      s2 = fmaf(v.x, v.x, s2); s2 = fmaf(v.y, v.y, s2);
      s2 = fmaf(v.z, v.z, s2); s2 = fmaf(v.w, v.w, s2);
    }
#pragma unroll
    for (int o = 1; o < 8; o <<= 1) {
      s1 += __shfl_xor(s1, o, 64);
      s2 += __shfl_xor(s2, o, 64);
    }
    if (k == 0) {
      float m = s1 * (1.f / kDM);
      mrow[row] = m;
      irow[row] = rsqrtf(s2 * (1.f / kDM) - m * m + 1e-5f);
    }
  }
  __syncthreads();

  // ---- LN1 apply in place ----
#pragma unroll
  for (int t = 0; t < kCHUNK; ++t)
    hbuf[t][d] = fmaf((hbuf[t][d] - mrow[t]) * irow[t], g1, b1);
  __syncthreads();

  // ---- attn hidden GEMV: weights loaded HERE (short live range) ----
  float p[kCHUNK];
  {
    float wreg[32];
    const float* wp = ca1_w + (sub * 32) * 32 + j;
#pragma unroll
    for (int k = 0; k < 32; ++k) wreg[k] = wp[k * 32];
#pragma unroll
    for (int t = 0; t < kCHUNK; ++t) {
      float acc = 0.f;
#pragma unroll
      for (int qq = 0; qq < 8; ++qq) {
        int q = (qq + 2 * sub) & 7;
        float4 v = *(const float4*)&hbuf[t][sub * 32 + q * 4];
        acc = fmaf(v.x, wreg[q * 4 + 0], acc);
        acc = fmaf(v.y, wreg[q * 4 + 1], acc);
        acc = fmaf(v.z, wreg[q * 4 + 2], acc);
        acc = fmaf(v.w, wreg[q * 4 + 3], acc);
      }
      p[t] = acc;
    }
  }
#pragma unroll
  for (int t = 0; t < kCHUNK; ++t) p[t] += __shfl_xor(p[t], 32, 64);
  if (sub == 2) {
#pragma unroll
    for (int t = 0; t < kCHUNK; ++t) part[t][j] = p[t];
  }
  __syncthreads();

  // ---- wave0: hid, scores, softmax — in registers ----
  if (tid < 64) {
    float bj = ca1_b[j];
    float w2 = ca2_w[j];
#pragma unroll
    for (int t = 0; t < kCHUNK; ++t)
      p[t] = fast_tanh(p[t] + part[t][j] + bj) * w2;
#pragma unroll
    for (int o = 16; o; o >>= 1)
#pragma unroll
      for (int t = 0; t < kCHUNK; ++t) p[t] += __shfl_xor(p[t], o, 64);
    float mx = p[0];
#pragma unroll
    for (int t = 1; t < kCHUNK; ++t) mx = fmaxf(mx, p[t]);
    float e[kCHUNK], ssum = 0.f;
#pragma unroll
    for (int t = 0; t < kCHUNK; ++t) { e[t] = __expf(p[t] - mx); ssum += e[t]; }
    float inv = 1.f / ssum;
    if (tid == 0) {
      float4* w4 = (float4*)wl;
      w4[0] = make_float4(e[0]  * inv, e[1]  * inv, e[2]  * inv, e[3]  * inv);
      w4[1] = make_float4(e[4]  * inv, e[5]  * inv, e[6]  * inv, e[7]  * inv);
      w4[2] = make_float4(e[8]  * inv, e[9]  * inv, e[10] * inv, e[11] * inv);
      w4[3] = make_float4(e[12] * inv, e[13] * inv, e[14] * inv, e[15] * inv);
    }
  }
  __syncthreads();

  // ---- weighted sum -> summ ----
  {
    float acc = 0.f;
    const float4* w4 = (const float4*)wl;
#pragma unroll
    for (int tq = 0; tq < 4; ++tq) {
      float4 wv = w4[tq];
      acc = fmaf(wv.x, hbuf[tq * 4 + 0][d], acc);
      acc = fmaf(wv.y, hbuf[tq * 4 + 1][d], acc);
      acc = fmaf(wv.z, hbuf[tq * 4 + 2][d], acc);
      acc = fmaf(wv.w, hbuf[tq * 4 + 3][d], acc);
    }
    summ[d] = acc;
  }
  __syncthreads();

  // ---- projections + parallel sincos (native) ----
  if (tid < kNP) {
    float acc = pp_b[tid];
    const float4* s4 = (const float4*)summ;
#pragma unroll 8
    for (int q = 0; q < 32; ++q) {
      float4 v = s4[q];
      acc = fmaf(v.x, pp_w[(q * 4 + 0) * kNP + tid], acc);
      acc = fmaf(v.y, pp_w[(q * 4 + 1) * kNP + tid], acc);
      acc = fmaf(v.z, pp_w[(q * 4 + 2) * kNP + tid], acc);
      acc = fmaf(v.w, pp_w[(q * 4 + 3) * kNP + tid], acc);
    }
    csb[6 + tid] = make_float2(__cosf(0.5f * acc), __sinf(0.5f * acc));
  } else if (tid < kNP + kNQ) {
    int jj = tid - kNP;
    float acc = ep_b[jj];
    for (int dd = 0; dd < kDM; ++dd) acc = fmaf(summ[dd], ep_w[dd * kNQ + jj], acc);
    float a = fast_tanh(acc) * kPI;
    csb[jj] = make_float2(__cosf(0.5f * a), __sinf(0.5f * a));
  }

  // ---- epilogue weights issued here: loads fly during the circuit ----
  float ow[3 * kNQ];
#pragma unroll
  for (int jj = 0; jj < 3 * kNQ; ++jj) ow[jj] = op_w[jj * kDM + d];
  float g2 = ln2_g[d], b2 = ln2_b[d], ob = op_b[d];
  __syncthreads();

  // ---- 6-qubit circuit on wave 0 ----
  if (tid < 64) {
    int lane = tid;
    float ar = (lane == 0) ? 1.f : 0.f;
    float ai = 0.f;
#pragma unroll
    for (int i = 0; i < kNQ; ++i) g_ry(csb[i], i, lane, ar, ai);
    apply_ansatz(csb + 6,      lane, ar, ai);
    apply_ansatz(csb + 6 + 30, lane, ar, ai);
    apply_ansatz(csb + 6 + 60, lane, ar, ai);
    apply_ansatz(csb + 6 + 90, lane, ar, ai);

#pragma unroll
    for (int i = 0; i < kNQ; ++i) {
      int m = 1 << (5 - i);
      float pr = __shfl_xor(ar, m, 64);
      float pi = __shfl_xor(ai, m, 64);
      int bit = (lane >> (5 - i)) & 1;
      float nrm = fmaf(ar, ar, ai * ai);
      float abr, abi, zz;
      if (bit) { abr = 0.f; abi = 0.f; zz = -nrm; }
      else {
        abr = fmaf(ar, pr,  ai * pi);
        abi = fmaf(ar, pi, -ai * pr);
        zz  = nrm;
      }
#pragma unroll
      for (int o = 32; o; o >>= 1) {
        abr += __shfl_xor(abr, o, 64);
        abi += __shfl_xor(abi, o, 64);
        zz  += __shfl_xor(zz,  o, 64);
      }
      if (lane == 0) { qv[i] = 2.f * abr; qv[kNQ + i] = 2.f * abi; qv[2 * kNQ + i] = zz; }
    }
  }
  __syncthreads();

  // ---- cf = silu(LN2(q @ op_w + op_b)) ----
  float cfv;
  {
    float acc = ob;
#pragma unroll
    for (int jj = 0; jj < 3 * kNQ; ++jj) acc = fmaf(qv[jj], ow[jj], acc);
    float v = acc, v2 = acc * acc;
#pragma unroll
    for (int o = 32; o; o >>= 1) { v += __shfl_xor(v, o, 64); v2 += __shfl_xor(v2, o, 64); }
    int wv = tid >> 6;
    if ((tid & 63) == 0) { red[wv] = v; red[2 + wv] = v2; }
    __syncthreads();
    float s1 = red[0] + red[1], s2 = red[2] + red[3];
    float m   = s1 * (1.f / kDM);
    float var = s2 * (1.f / kDM) - m * m;
    float xn  = fmaf((acc - m) * rsqrtf(var + 1e-5f), g2, b2);
    cfv = fast_silu(xn);
    cf[chunk * kDM + d] = cfv;
    hbuf[0][d] = cfv;                        // stage for fused score
  }
  __syncthreads();

  // ---- fused seq-attention score (old k_scl) ----
  {
    float acc2 = 0.f;
    const float* wp2 = sa1_w + (sub * 32) * 32 + j;
#pragma unroll
    for (int k = 0; k < 32; ++k)
      acc2 = fmaf(hbuf[0][sub * 32 + k], wp2[k * 32], acc2);
    acc2 += __shfl_xor(acc2, 32, 64);        // wave0 lanes0-31: dd 0..63; wave1: dd 64..127
    if (sub == 2) hbuf[1][j] = acc2;
    __syncthreads();
    if (tid < 32) {
      float hv = fast_tanh(acc2 + hbuf[1][j] + sa1_b[j]);
      float v  = hv * sa2_w[j];
#pragma unroll
      for (int o = 16; o; o >>= 1) v += __shfl_xor(v, o, 64);
      if (j == 0) sclb[chunk] = v + sa2_b[0];
    }
  }
}

// ---------------------------------------------------------------------------
// k_pool: one block (256 thr) per batch: softmax over 128 + half-split pooled
// rep + 4-way-split classifier.

__global__ __launch_bounds__(256) void k_pool(
    const float* __restrict__ cf, const float* __restrict__ scl,
    const float* __restrict__ cl1_w, const float* __restrict__ cl1_b,
    const float* __restrict__ cl2_w, const float* __restrict__ cl2_b,
    float* __restrict__ out)
{
  __shared__ float wl[kNCH];
  __shared__ float rep2[2][kDM];
  __shared__ float ulp[4][64];
  __shared__ float ul[64];
  __shared__ float red2[8];

  int b = blockIdx.x, tid = threadIdx.x;
  int idx = tid & 127;
  int wid = tid >> 6;                        // wave 0..3

  float s = scl[b * kNCH + idx];
  float mx = s;
#pragma unroll
  for (int o = 32; o; o >>= 1) mx = fmaxf(mx, __shfl_xor(mx, o, 64));
  if ((tid & 63) == 0) red2[wid] = mx;
  __syncthreads();
  mx = fmaxf(fmaxf(red2[0], red2[1]), fmaxf(red2[2], red2[3]));
  float e = __expf(s - mx);
  float se = e;
#pragma unroll
  for (int o = 32; o; o >>= 1) se += __shfl_xor(se, o, 64);
  if ((tid & 63) == 0) red2[4 + wid] = se;
  if (tid < kNCH) wl[tid] = e;               // waves 0,1 cover 0..127 exactly
  __syncthreads();
  float inv = 1.f / (red2[4] + red2[5]);

  // ---- pooling: half h sums 64 chunks ----
  {
    int d = tid & 127, half = tid >> 7;
    const float* cfb = cf + (size_t)b * kNCH * kDM + (size_t)half * 64 * kDM;
    const float* wlh = wl + half * 64;
    float a0 = 0.f, a1 = 0.f, a2 = 0.f, a3 = 0.f;
#pragma unroll 4
    for (int ncc = 0; ncc < 64; ncc += 4) {
      a0 = fmaf(wlh[ncc + 0], cfb[(ncc + 0) * kDM + d], a0);
      a1 = fmaf(wlh[ncc + 1], cfb[(ncc + 1) * kDM + d], a1);
      a2 = fmaf(wlh[ncc + 2], cfb[(ncc + 2) * kDM + d], a2);
      a3 = fmaf(wlh[ncc + 3], cfb[(ncc + 3) * kDM + d], a3);
    }
    rep2[half][d] = (a0 + a1) + (a2 + a3);
  }
  __syncthreads();

  // ---- cl1: output j, quarter qq over dd ----
  {
    int jj = tid & 63, qq = tid >> 6;
    float accp = 0.f;
#pragma unroll 8
    for (int k = 0; k < 32; ++k) {
      int dd = qq * 32 + k;
      float rv = (rep2[0][dd] + rep2[1][dd]) * inv;
      accp = fmaf(rv, cl1_w[dd * 64 + jj], accp);
    }
    ulp[qq][jj] = accp;
  }
  __syncthreads();

  if (tid < 64) {
    float acc = cl1_b[tid] + ((ulp[0][tid] + ulp[1][tid]) + (ulp[2][tid] + ulp[3][tid]));
    ul[tid] = fast_silu(acc);
  }
  __syncthreads();

  if (tid < 2) {
    float acc = cl2_b[tid];
#pragma unroll
    for (int k = 0; k < 64; ++k) acc = fmaf(ul[k], cl2_w[k * 2 + tid], acc);
    out[b * 2 + tid] = acc;
  }
}

// ---------------------------------------------------------------------------

extern "C" void kernel_launch(void* const* d_in, const int* in_sizes, int n_in,
                              void* d_out, int out_size, void* d_ws, size_t ws_size,
                              hipStream_t stream) {
  const float* x      = (const float*)d_in[0];
  const float* conv_w = (const float*)d_in[1];
  const float* conv_b = (const float*)d_in[2];
  const float* ln1_g  = (const float*)d_in[3];
  const float* ln1_b  = (const float*)d_in[4];
  const float* ca1_w  = (const float*)d_in[5];
  const float* ca1_b  = (const float*)d_in[6];
  const float* ca2_w  = (const float*)d_in[7];
  const float* ca2_b  = (const float*)d_in[8];
  const float* pp_w   = (const float*)d_in[9];
  const float* pp_b   = (const float*)d_in[10];
  const float* ep_w   = (const float*)d_in[11];
  const float* ep_b   = (const float*)d_in[12];
  const float* op_w   = (const float*)d_in[13];
  const float* op_b   = (const float*)d_in[14];
  const float* ln2_g  = (const float*)d_in[15];
  const float* ln2_b  = (const float*)d_in[16];
  const float* sa1_w  = (const float*)d_in[17];
  const float* sa1_b  = (const float*)d_in[18];
  const float* sa2_w  = (const float*)d_in[19];
  const float* sa2_b  = (const float*)d_in[20];
  const float* cl1_w  = (const float*)d_in[21];
  const float* cl1_b  = (const float*)d_in[22];
  const float* cl2_w  = (const float*)d_in[23];
  const float* cl2_b  = (const float*)d_in[24];
  float* out  = (float*)d_out;
  float* cf   = (float*)d_ws;                               // 16384*128 f32 = 8 MB
  float* sclb = (float*)d_ws + (size_t)kBATCH * kNCH * kDM; // 16384 f32

  k_chunk<<<kBATCH * kNCH, 128, 0, stream>>>(
      x, conv_w, conv_b, ln1_g, ln1_b, ca1_w, ca1_b, ca2_w, ca2_b,
      pp_w, pp_b, ep_w, ep_b, op_w, op_b, ln2_g, ln2_b,
      sa1_w, sa1_b, sa2_w, sa2_b, cf, sclb);
  k_pool<<<kBATCH, 256, 0, stream>>>(
      cf, sclb, cl1_w, cl1_b, cl2_w, cl2_b, out);
}

// Round 6
// 345.037 us; speedup vs baseline: 1.2102x; 1.2102x over previous
//
#include <hip/hip_runtime.h>
#include <math.h>

// ---------------------------------------------------------------------------
// QuantumTransformerE2E on MI355X — R6 (= R5 resubmitted; R5 bench died in
// harness infra, no counters). k_chunk: no min-waves launch bound (the
// __launch_bounds__(128,6) of R3/R4 capped VGPR at 40 and caused ~262 MB of
// scratch spill traffic). Early weight issue (overlap halo/conv/LN). Fused
// seq-score tail. k_pool: 512 threads, 4-way pooling, 8-way cl1.
// ---------------------------------------------------------------------------

constexpr int kNQ    = 6;
constexpr int kDM    = 128;
constexpr int kCH    = 4;
constexpr int kSEQ   = 2048;
constexpr int kCHUNK = 16;
constexpr int kBATCH = 128;
constexpr int kNCH   = kSEQ / kCHUNK;  // 128
constexpr int kNP    = 120;
constexpr float kPI  = 3.14159265358979323846f;

__device__ __forceinline__ float fast_tanh(float x) {
  float e = __expf(-2.f * fabsf(x));
  float r = (1.f - e) * __builtin_amdgcn_rcpf(1.f + e);
  return copysignf(r, x);
}

__device__ __forceinline__ float fast_silu(float x) {
  return x * __builtin_amdgcn_rcpf(1.f + __expf(-x));
}

// ---- gates: cs = (cos(t/2), sin(t/2)); qubit w <-> bit (5-w) of lane ------

__device__ __forceinline__ void g_rx(float2 cs, int w, int lane, float& ar, float& ai) {
  int m = 1 << (5 - w);
  float pr = __shfl_xor(ar, m, 64);
  float pi = __shfl_xor(ai, m, 64);
  float nr = fmaf(cs.x, ar,  cs.y * pi);
  float ni = fmaf(cs.x, ai, -cs.y * pr);
  ar = nr; ai = ni;
}

__device__ __forceinline__ void g_ry(float2 cs, int w, int lane, float& ar, float& ai) {
  int m = 1 << (5 - w);
  float pr = __shfl_xor(ar, m, 64);
  float pi = __shfl_xor(ai, m, 64);
  float sg = ((lane >> (5 - w)) & 1) ? cs.y : -cs.y;
  float nr = fmaf(cs.x, ar, sg * pr);
  float ni = fmaf(cs.x, ai, sg * pi);
  ar = nr; ai = ni;
}

__device__ __forceinline__ void g_rz(float2 cs, int w, int lane, float& ar, float& ai) {
  float sp = ((lane >> (5 - w)) & 1) ? cs.y : -cs.y;
  float nr = fmaf(ar, cs.x, -ai * sp);
  float ni = fmaf(ar, sp,  ai * cs.x);
  ar = nr; ai = ni;
}

__device__ __forceinline__ void g_crx(float2 cs, int w0, int w1, int lane, float& ar, float& ai) {
  int m = 1 << (5 - w1);
  float pr = __shfl_xor(ar, m, 64);
  float pi = __shfl_xor(ai, m, 64);
  if ((lane >> (5 - w0)) & 1) {
    float nr = fmaf(cs.x, ar,  cs.y * pi);
    float ni = fmaf(cs.x, ai, -cs.y * pr);
    ar = nr; ai = ni;
  }
}

__device__ __forceinline__ void apply_ansatz(const float2* cs, int lane, float& ar, float& ai) {
#pragma unroll
  for (int i = 0; i < kNQ; ++i) {
    g_rx(cs[3 * i + 0], i, lane, ar, ai);
    g_ry(cs[3 * i + 1], i, lane, ar, ai);
    g_rz(cs[3 * i + 2], i, lane, ar, ai);
  }
  int off = 3 * kNQ;
#pragma unroll
  for (int i = 0; i < kNQ; ++i) g_crx(cs[off++], i, (i + 1) % kNQ, lane, ar, ai);
#pragma unroll
  for (int i = kNQ - 1; i >= 0; --i) g_crx(cs[off++], i, (i + 5) % kNQ, lane, ar, ai);
}

// ---------------------------------------------------------------------------

__global__ __launch_bounds__(128) void k_chunk(
    const float* __restrict__ x,
    const float* __restrict__ conv_w, const float* __restrict__ conv_b,
    const float* __restrict__ ln1_g,  const float* __restrict__ ln1_b,
    const float* __restrict__ ca1_w,  const float* __restrict__ ca1_b,
    const float* __restrict__ ca2_w,  const float* __restrict__ ca2_b,
    const float* __restrict__ pp_w,   const float* __restrict__ pp_b,
    const float* __restrict__ ep_w,   const float* __restrict__ ep_b,
    const float* __restrict__ op_w,   const float* __restrict__ op_b,
    const float* __restrict__ ln2_g,  const float* __restrict__ ln2_b,
    const float* __restrict__ sa1_w,  const float* __restrict__ sa1_b,
    const float* __restrict__ sa2_w,  const float* __restrict__ sa2_b,
    float* __restrict__ cf, float* __restrict__ sclb)
{
  __shared__ float hbuf[kCHUNK][132];        // 8448 B, rows 16B-aligned
  __shared__ __align__(16) float Bu[512];    // 2048 B overlaid union region
  __shared__ float mrow[kCHUNK], irow[kCHUNK];
  __shared__ float red[4];

  // union views (disjoint lifetimes):
  float (*xs)[kCHUNK + 2] = (float(*)[kCHUNK + 2])Bu;  // [4][18], conv halo
  float (*part)[32]       = (float(*)[32])Bu;          // [16][32], GEMV partials
  float*  summ = Bu;                                   // [128]
  float*  wl   = Bu + 128;                             // [16]
  float*  qv   = Bu + 144;                             // [18]
  float2* csb  = (float2*)(Bu + 164);                  // [126]

  const int tid   = threadIdx.x;
  const int chunk = blockIdx.x;
  const int b     = chunk >> 7;
  const int nc    = chunk & 127;
  const int t0    = nc * kCHUNK;
  const int d     = tid;
  const int j     = tid & 31;
  const int sub   = tid >> 5;                // 0..3

  // ---- early global loads (fly under halo/conv/LN) ----
  float w12[12];
  {
    const float4* cw = (const float4*)(conv_w + d * 12);
    float4 a0 = cw[0], a1 = cw[1], a2 = cw[2];
    w12[0] = a0.x; w12[1]  = a0.y; w12[2]  = a0.z; w12[3]  = a0.w;
    w12[4] = a1.x; w12[5]  = a1.y; w12[6]  = a1.z; w12[7]  = a1.w;
    w12[8] = a2.x; w12[9]  = a2.y; w12[10] = a2.z; w12[11] = a2.w;
  }
  float cb = conv_b[d];
  float g1 = ln1_g[d], b1 = ln1_b[d];
  float wreg[32];
  {
    const float* wp = ca1_w + (sub * 32) * 32 + j;
#pragma unroll
    for (int k = 0; k < 32; ++k) wreg[k] = wp[k * 32];
  }

  // ---- stage x halo ----
  if (tid < kCH * (kCHUNK + 2)) {
    int ch  = tid / (kCHUNK + 2);
    int pos = tid % (kCHUNK + 2);
    int s   = t0 - 1 + pos;
    float v = 0.f;
    if (s >= 0 && s < kSEQ) v = x[(b * kCH + ch) * kSEQ + s];
    xs[ch][pos] = v;
  }
  __syncthreads();

  // ---- conv1d -> hbuf ----
#pragma unroll
  for (int t = 0; t < kCHUNK; ++t) {
    float acc = cb;
#pragma unroll
    for (int ch = 0; ch < kCH; ++ch)
#pragma unroll
      for (int k = 0; k < 3; ++k)
        acc = fmaf(xs[ch][t + k], w12[ch * 3 + k], acc);
    hbuf[t][d] = acc;
  }
  __syncthreads();

  // ---- LN1 stats: 8 lanes per row, shfl combine ----
  {
    int row = tid >> 3, k = tid & 7;
    const float4* rp = (const float4*)&hbuf[row][k * 16];
    float s1 = 0.f, s2 = 0.f;
#pragma unroll
    for (int q = 0; q < 4; ++q) {
      float4 v = rp[q];
      s1 += v.x + v.y + v.z + v.w;
      s2 = fmaf(v.x, v.x, s2); s2 = fmaf(v.y, v.y, s2);
      s2 = fmaf(v.z, v.z, s2); s2 = fmaf(v.w, v.w, s2);
    }
#pragma unroll
    for (int o = 1; o < 8; o <<= 1) {
      s1 += __shfl_xor(s1, o, 64);
      s2 += __shfl_xor(s2, o, 64);
    }
    if (k == 0) {
      float m = s1 * (1.f / kDM);
      mrow[row] = m;
      irow[row] = rsqrtf(s2 * (1.f / kDM) - m * m + 1e-5f);
    }
  }
  __syncthreads();

  // ---- LN1 apply in place ----
#pragma unroll
  for (int t = 0; t < kCHUNK; ++t)
    hbuf[t][d] = fmaf((hbuf[t][d] - mrow[t]) * irow[t], g1, b1);
  __syncthreads();

  // ---- attn hidden GEMV: sub-split over dd, rotated reads ----
  float p[kCHUNK];
#pragma unroll
  for (int t = 0; t < kCHUNK; ++t) {
    float acc = 0.f;
#pragma unroll
    for (int qq = 0; qq < 8; ++qq) {
      int q = (qq + 2 * sub) & 7;
      float4 v = *(const float4*)&hbuf[t][sub * 32 + q * 4];
      acc = fmaf(v.x, wreg[q * 4 + 0], acc);
      acc = fmaf(v.y, wreg[q * 4 + 1], acc);
      acc = fmaf(v.z, wreg[q * 4 + 2], acc);
      acc = fmaf(v.w, wreg[q * 4 + 3], acc);
    }
    p[t] = acc;
  }
#pragma unroll
  for (int t = 0; t < kCHUNK; ++t) p[t] += __shfl_xor(p[t], 32, 64);
  if (sub == 2) {
#pragma unroll
    for (int t = 0; t < kCHUNK; ++t) part[t][j] = p[t];
  }
  __syncthreads();

  // ---- wave0: hid, scores, softmax — in registers ----
  if (tid < 64) {
    float bj = ca1_b[j];
    float w2 = ca2_w[j];
#pragma unroll
    for (int t = 0; t < kCHUNK; ++t)
      p[t] = fast_tanh(p[t] + part[t][j] + bj) * w2;
#pragma unroll
    for (int o = 16; o; o >>= 1)
#pragma unroll
      for (int t = 0; t < kCHUNK; ++t) p[t] += __shfl_xor(p[t], o, 64);
    float mx = p[0];
#pragma unroll
    for (int t = 1; t < kCHUNK; ++t) mx = fmaxf(mx, p[t]);
    float e[kCHUNK], ssum = 0.f;
#pragma unroll
    for (int t = 0; t < kCHUNK; ++t) { e[t] = __expf(p[t] - mx); ssum += e[t]; }
    float inv = 1.f / ssum;
    if (tid == 0) {
      float4* w4 = (float4*)wl;
      w4[0] = make_float4(e[0]  * inv, e[1]  * inv, e[2]  * inv, e[3]  * inv);
      w4[1] = make_float4(e[4]  * inv, e[5]  * inv, e[6]  * inv, e[7]  * inv);
      w4[2] = make_float4(e[8]  * inv, e[9]  * inv, e[10] * inv, e[11] * inv);
      w4[3] = make_float4(e[12] * inv, e[13] * inv, e[14] * inv, e[15] * inv);
    }
  }
  __syncthreads();

  // ---- weighted sum -> summ ----
  {
    float acc = 0.f;
    const float4* w4 = (const float4*)wl;
#pragma unroll
    for (int tq = 0; tq < 4; ++tq) {
      float4 wv = w4[tq];
      acc = fmaf(wv.x, hbuf[tq * 4 + 0][d], acc);
      acc = fmaf(wv.y, hbuf[tq * 4 + 1][d], acc);
      acc = fmaf(wv.z, hbuf[tq * 4 + 2][d], acc);
      acc = fmaf(wv.w, hbuf[tq * 4 + 3][d], acc);
    }
    summ[d] = acc;
  }
  __syncthreads();

  // ---- projections + parallel sincos (native) ----
  if (tid < kNP) {
    float acc = pp_b[tid];
    const float4* s4 = (const float4*)summ;
#pragma unroll 8
    for (int q = 0; q < 32; ++q) {
      float4 v = s4[q];
      acc = fmaf(v.x, pp_w[(q * 4 + 0) * kNP + tid], acc);
      acc = fmaf(v.y, pp_w[(q * 4 + 1) * kNP + tid], acc);
      acc = fmaf(v.z, pp_w[(q * 4 + 2) * kNP + tid], acc);
      acc = fmaf(v.w, pp_w[(q * 4 + 3) * kNP + tid], acc);
    }
    csb[6 + tid] = make_float2(__cosf(0.5f * acc), __sinf(0.5f * acc));
  } else if (tid < kNP + kNQ) {
    int jj = tid - kNP;
    float acc = ep_b[jj];
    for (int dd = 0; dd < kDM; ++dd) acc = fmaf(summ[dd], ep_w[dd * kNQ + jj], acc);
    float a = fast_tanh(acc) * kPI;
    csb[jj] = make_float2(__cosf(0.5f * a), __sinf(0.5f * a));
  }

  // ---- epilogue weights issued here: loads fly during the circuit ----
  float ow[3 * kNQ];
#pragma unroll
  for (int jj = 0; jj < 3 * kNQ; ++jj) ow[jj] = op_w[jj * kDM + d];
  float g2 = ln2_g[d], b2 = ln2_b[d], ob = op_b[d];
  __syncthreads();

  // ---- 6-qubit circuit on wave 0 ----
  if (tid < 64) {
    int lane = tid;
    float ar = (lane == 0) ? 1.f : 0.f;
    float ai = 0.f;
#pragma unroll
    for (int i = 0; i < kNQ; ++i) g_ry(csb[i], i, lane, ar, ai);
    apply_ansatz(csb + 6,      lane, ar, ai);
    apply_ansatz(csb + 6 + 30, lane, ar, ai);
    apply_ansatz(csb + 6 + 60, lane, ar, ai);
    apply_ansatz(csb + 6 + 90, lane, ar, ai);

#pragma unroll
    for (int i = 0; i < kNQ; ++i) {
      int m = 1 << (5 - i);
      float pr = __shfl_xor(ar, m, 64);
      float pi = __shfl_xor(ai, m, 64);
      int bit = (lane >> (5 - i)) & 1;
      float nrm = fmaf(ar, ar, ai * ai);
      float abr, abi, zz;
      if (bit) { abr = 0.f; abi = 0.f; zz = -nrm; }
      else {
        abr = fmaf(ar, pr,  ai * pi);
        abi = fmaf(ar, pi, -ai * pr);
        zz  = nrm;
      }
#pragma unroll
      for (int o = 32; o; o >>= 1) {
        abr += __shfl_xor(abr, o, 64);
        abi += __shfl_xor(abi, o, 64);
        zz  += __shfl_xor(zz,  o, 64);
      }
      if (lane == 0) { qv[i] = 2.f * abr; qv[kNQ + i] = 2.f * abi; qv[2 * kNQ + i] = zz; }
    }
  }
  __syncthreads();

  // ---- cf = silu(LN2(q @ op_w + op_b)) ----
  float cfv;
  {
    float acc = ob;
#pragma unroll
    for (int jj = 0; jj < 3 * kNQ; ++jj) acc = fmaf(qv[jj], ow[jj], acc);
    float v = acc, v2 = acc * acc;
#pragma unroll
    for (int o = 32; o; o >>= 1) { v += __shfl_xor(v, o, 64); v2 += __shfl_xor(v2, o, 64); }
    int wv = tid >> 6;
    if ((tid & 63) == 0) { red[wv] = v; red[2 + wv] = v2; }
    __syncthreads();
    float s1 = red[0] + red[1], s2 = red[2] + red[3];
    float m   = s1 * (1.f / kDM);
    float var = s2 * (1.f / kDM) - m * m;
    float xn  = fmaf((acc - m) * rsqrtf(var + 1e-5f), g2, b2);
    cfv = fast_silu(xn);
    cf[chunk * kDM + d] = cfv;
    hbuf[0][d] = cfv;                        // stage for fused score
  }
  __syncthreads();

  // ---- fused seq-attention score (old k_scl) ----
  {
    float acc2 = 0.f;
    const float* wp2 = sa1_w + (sub * 32) * 32 + j;
#pragma unroll
    for (int k = 0; k < 32; ++k)
      acc2 = fmaf(hbuf[0][sub * 32 + k], wp2[k * 32], acc2);
    acc2 += __shfl_xor(acc2, 32, 64);
    if (sub == 2) hbuf[1][j] = acc2;
    __syncthreads();
    if (tid < 32) {
      float hv = fast_tanh(acc2 + hbuf[1][j] + sa1_b[j]);
      float v  = hv * sa2_w[j];
#pragma unroll
      for (int o = 16; o; o >>= 1) v += __shfl_xor(v, o, 64);
      if (j == 0) sclb[chunk] = v + sa2_b[0];
    }
  }
}

// ---------------------------------------------------------------------------
// k_pool: one block (512 thr) per batch: softmax over 128 + 4-way-split
// pooling + 8-way-split cl1 + cl2.

__global__ __launch_bounds__(512) void k_pool(
    const float* __restrict__ cf, const float* __restrict__ scl,
    const float* __restrict__ cl1_w, const float* __restrict__ cl1_b,
    const float* __restrict__ cl2_w, const float* __restrict__ cl2_b,
    float* __restrict__ out)
{
  __shared__ float wl[kNCH];
  __shared__ float rep4[4][kDM];
  __shared__ float ulp[8][64];
  __shared__ float ul[64];
  __shared__ float red2[16];

  int b = blockIdx.x, tid = threadIdx.x;
  int idx = tid & 127;
  int wid = tid >> 6;                        // wave 0..7

  float s = scl[b * kNCH + idx];
  float mx = s;
#pragma unroll
  for (int o = 32; o; o >>= 1) mx = fmaxf(mx, __shfl_xor(mx, o, 64));
  if ((tid & 63) == 0) red2[wid] = mx;
  __syncthreads();
  mx = fmaxf(red2[0], red2[1]);
  float e = __expf(s - mx);
  float se = e;
#pragma unroll
  for (int o = 32; o; o >>= 1) se += __shfl_xor(se, o, 64);
  if ((tid & 63) == 0) red2[8 + wid] = se;
  if (tid < kNCH) wl[tid] = e;
  __syncthreads();
  float inv = 1.f / (red2[8] + red2[9]);

  // ---- pooling: quarter qq sums 32 chunks ----
  {
    int dd = tid & 127, qq = tid >> 7;       // 0..3
    const float* cfb = cf + (size_t)b * kNCH * kDM + (size_t)qq * 32 * kDM;
    const float* wlq = wl + qq * 32;
    float a0 = 0.f, a1 = 0.f, a2 = 0.f, a3 = 0.f;
#pragma unroll 4
    for (int ncc = 0; ncc < 32; ncc += 4) {
      a0 = fmaf(wlq[ncc + 0], cfb[(ncc + 0) * kDM + dd], a0);
      a1 = fmaf(wlq[ncc + 1], cfb[(ncc + 1) * kDM + dd], a1);
      a2 = fmaf(wlq[ncc + 2], cfb[(ncc + 2) * kDM + dd], a2);
      a3 = fmaf(wlq[ncc + 3], cfb[(ncc + 3) * kDM + dd], a3);
    }
    rep4[qq][dd] = (a0 + a1) + (a2 + a3);
  }
  __syncthreads();

  // ---- cl1: output j, eighth qq over dd ----
  {
    int jj = tid & 63, qq = tid >> 6;        // 0..7
    float accp = 0.f;
#pragma unroll
    for (int k = 0; k < 16; ++k) {
      int dd = qq * 16 + k;
      float rv = ((rep4[0][dd] + rep4[1][dd]) + (rep4[2][dd] + rep4[3][dd])) * inv;
      accp = fmaf(rv, cl1_w[dd * 64 + jj], accp);
    }
    ulp[qq][jj] = accp;
  }
  __syncthreads();

  if (tid < 64) {
    float acc = cl1_b[tid];
#pragma unroll
    for (int q = 0; q < 8; ++q) acc += ulp[q][tid];
    ul[tid] = fast_silu(acc);
  }
  __syncthreads();

  if (tid < 2) {
    float acc = cl2_b[tid];
#pragma unroll
    for (int k = 0; k < 64; ++k) acc = fmaf(ul[k], cl2_w[k * 2 + tid], acc);
    out[b * 2 + tid] = acc;
  }
}

// ---------------------------------------------------------------------------

extern "C" void kernel_launch(void* const* d_in, const int* in_sizes, int n_in,
                              void* d_out, int out_size, void* d_ws, size_t ws_size,
                              hipStream_t stream) {
  const float* x      = (const float*)d_in[0];
  const float* conv_w = (const float*)d_in[1];
  const float* conv_b = (const float*)d_in[2];
  const float* ln1_g  = (const float*)d_in[3];
  const float* ln1_b  = (const float*)d_in[4];
  const float* ca1_w  = (const float*)d_in[5];
  const float* ca1_b  = (const float*)d_in[6];
  const float* ca2_w  = (const float*)d_in[7];
  const float* ca2_b  = (const float*)d_in[8];
  const float* pp_w   = (const float*)d_in[9];
  const float* pp_b   = (const float*)d_in[10];
  const float* ep_w   = (const float*)d_in[11];
  const float* ep_b   = (const float*)d_in[12];
  const float* op_w   = (const float*)d_in[13];
  const float* op_b   = (const float*)d_in[14];
  const float* ln2_g  = (const float*)d_in[15];
  const float* ln2_b  = (const float*)d_in[16];
  const float* sa1_w  = (const float*)d_in[17];
  const float* sa1_b  = (const float*)d_in[18];
  const float* sa2_w  = (const float*)d_in[19];
  const float* sa2_b  = (const float*)d_in[20];
  const float* cl1_w  = (const float*)d_in[21];
  const float* cl1_b  = (const float*)d_in[22];
  const float* cl2_w  = (const float*)d_in[23];
  const float* cl2_b  = (const float*)d_in[24];
  float* out  = (float*)d_out;
  float* cf   = (float*)d_ws;                               // 16384*128 f32 = 8 MB
  float* sclb = (float*)d_ws + (size_t)kBATCH * kNCH * kDM; // 16384 f32

  k_chunk<<<kBATCH * kNCH, 128, 0, stream>>>(
      x, conv_w, conv_b, ln1_g, ln1_b, ca1_w, ca1_b, ca2_w, ca2_b,
      pp_w, pp_b, ep_w, ep_b, op_w, op_b, ln2_g, ln2_b,
      sa1_w, sa1_b, sa2_w, sa2_b, cf, sclb);
  k_pool<<<kBATCH, 512, 0, stream>>>(
      cf, sclb, cl1_w, cl1_b, cl2_w, cl2_b, out);
}